// Round 1
// baseline (380.666 us; speedup 1.0000x reference)
//
#include <hip/hip_runtime.h>

// Problem constants (from reference)
#define NC   32      // feature channels
#define ND1  1024    // line resolution
#define ND2  256     // plane resolution
#define NM   64      // hidden width
#define NPIX (1024 * 1024)

// ---------------------------------------------------------------------------
// Transpose [32][N] -> [N][32], LDS-tiled (64 positions x 32 channels / block).
// Used for line tables (N=1024) and the plane viewed as [32][65536].
// ---------------------------------------------------------------------------
__global__ __launch_bounds__(256) void transpose32(const float* __restrict__ in,
                                                   float* __restrict__ out, int N) {
    __shared__ float tile[32][65];   // +1 pad: conflict-free on both phases
    const int pos0 = blockIdx.x * 64;
    const int tid  = threadIdx.x;
#pragma unroll
    for (int r = 0; r < 8; ++r) {
        int c = r * 4 + (tid >> 6);          // 0..31
        int p = tid & 63;                    // coalesced read along N
        tile[c][p] = in[c * N + pos0 + p];
    }
    __syncthreads();
#pragma unroll
    for (int r = 0; r < 8; ++r) {
        int p = r * 8 + (tid >> 5);          // 0..63
        int c = tid & 31;                    // coalesced write along C
        out[(pos0 + p) * 32 + c] = tile[c][p];
    }
}

// ---------------------------------------------------------------------------
// Fused: line-x * line-y + plane  ->  Linear(32->64) -> ReLU -> Linear(64->1)
// One thread per pixel. TRANS: tables are channel-last ([D][32]).
// ---------------------------------------------------------------------------
template <bool TRANS>
__global__ __launch_bounds__(256, 2) void fused_forward(
    const float* __restrict__ coords,
    const float* __restrict__ lx,    // TRANS ? [1024][32] : [32][1024]
    const float* __restrict__ ly,
    const float* __restrict__ pl,    // TRANS ? [65536][32] : [32][65536]
    const float* __restrict__ W1,    // [64][32]
    const float* __restrict__ b1,    // [64]
    const float* __restrict__ W2,    // [64]  (W2 is [1][64])
    const float* __restrict__ b2,    // [1]
    float* __restrict__ out)
{
    const int pix = blockIdx.x * 256 + threadIdx.x;
    const float2 xy = reinterpret_cast<const float2*>(coords)[pix];
    const float xn = xy.x * (2.0f / 1024.0f) - 1.0f;
    const float yn = xy.y * (2.0f / 1024.0f) - 1.0f;

    // ---- 1D line interp (border clamp, align_corners) ----
    float posx = fminf(fmaxf((xn + 1.0f) * 0.5f * 1023.0f, 0.0f), 1023.0f);
    int   ix   = min((int)posx, 1022);
    float wx   = posx - (float)ix;
    float omwx = 1.0f - wx;

    float posy = fminf(fmaxf((yn + 1.0f) * 0.5f * 1023.0f, 0.0f), 1023.0f);
    int   iy   = min((int)posy, 1022);
    float wy   = posy - (float)iy;
    float omwy = 1.0f - wy;

    // ---- plane bilinear (zeros padding, align_corners) ----
    float px  = (xn + 1.0f) * 0.5f * 255.0f;
    float py  = (yn + 1.0f) * 0.5f * 255.0f;
    float fx0 = floorf(px), fy0 = floorf(py);
    int   x0 = (int)fx0, y0 = (int)fy0;
    float pwx = px - fx0, pwy = py - fy0;
    int   x1 = x0 + 1, y1 = y0 + 1;
    // fold zero-padding validity into the 4 weights
    float vx0 = (x0 >= 0 && x0 < ND2) ? 1.0f : 0.0f;
    float vx1 = (x1 >= 0 && x1 < ND2) ? 1.0f : 0.0f;
    float vy0 = (y0 >= 0 && y0 < ND2) ? 1.0f : 0.0f;
    float vy1 = (y1 >= 0 && y1 < ND2) ? 1.0f : 0.0f;
    int xc0 = min(max(x0, 0), ND2 - 1), xc1 = min(max(x1, 0), ND2 - 1);
    int yc0 = min(max(y0, 0), ND2 - 1), yc1 = min(max(y1, 0), ND2 - 1);
    float w00 = (1.0f - pwy) * (1.0f - pwx) * vy0 * vx0;
    float w01 = (1.0f - pwy) * pwx          * vy0 * vx1;
    float w10 = pwy          * (1.0f - pwx) * vy1 * vx0;
    float w11 = pwy          * pwx          * vy1 * vx1;

    float feat[NC];

    if (TRANS) {
        const float4* ax0 = (const float4*)(lx + ix * NC);
        const float4* ax1 = (const float4*)(lx + (ix + 1) * NC);
        const float4* ay0 = (const float4*)(ly + iy * NC);
        const float4* ay1 = (const float4*)(ly + (iy + 1) * NC);
        const float4* p00 = (const float4*)(pl + (yc0 * ND2 + xc0) * NC);
        const float4* p01 = (const float4*)(pl + (yc0 * ND2 + xc1) * NC);
        const float4* p10 = (const float4*)(pl + (yc1 * ND2 + xc0) * NC);
        const float4* p11 = (const float4*)(pl + (yc1 * ND2 + xc1) * NC);
#pragma unroll
        for (int k = 0; k < 8; ++k) {
            float4 a0 = ax0[k], a1 = ax1[k];
            float4 c0 = ay0[k], c1 = ay1[k];
            float4 q00 = p00[k], q01 = p01[k], q10 = p10[k], q11 = p11[k];
#define FEAT_COMP(j, comp)                                                   \
            {                                                                \
                float fxv = a0.comp * omwx + a1.comp * wx;                   \
                float fyv = c0.comp * omwy + c1.comp * wy;                   \
                float fpv = q00.comp * w00 + q01.comp * w01 +                \
                            q10.comp * w10 + q11.comp * w11;                 \
                feat[k * 4 + j] = fxv * fyv + fpv;                           \
            }
            FEAT_COMP(0, x) FEAT_COMP(1, y) FEAT_COMP(2, z) FEAT_COMP(3, w)
#undef FEAT_COMP
        }
    } else {
        // fallback: original channel-first layout (scattered 4B gathers)
#pragma unroll
        for (int c = 0; c < NC; ++c) {
            float a0 = lx[c * ND1 + ix],  a1 = lx[c * ND1 + ix + 1];
            float c0 = ly[c * ND1 + iy],  c1 = ly[c * ND1 + iy + 1];
            const float* ps = pl + c * (ND2 * ND2);
            float q00 = ps[yc0 * ND2 + xc0], q01 = ps[yc0 * ND2 + xc1];
            float q10 = ps[yc1 * ND2 + xc0], q11 = ps[yc1 * ND2 + xc1];
            float fxv = a0 * omwx + a1 * wx;
            float fyv = c0 * omwy + c1 * wy;
            feat[c] = fxv * fyv + (q00 * w00 + q01 * w01 + q10 * w10 + q11 * w11);
        }
    }

    // ---- decoder: h = relu(W1 @ feat + b1); out = W2 @ h + b2 ----
    // W1/b1/W2/b2 addresses are thread-uniform -> scalar loads (SGPR), free.
    float acc = b2[0];
#pragma unroll 4
    for (int m = 0; m < NM; ++m) {
        const float4* wrow = (const float4*)(W1 + m * NC);
        float a = b1[m];
#pragma unroll
        for (int k = 0; k < 8; ++k) {
            float4 wv = wrow[k];
            a = fmaf(feat[k * 4 + 0], wv.x, a);
            a = fmaf(feat[k * 4 + 1], wv.y, a);
            a = fmaf(feat[k * 4 + 2], wv.z, a);
            a = fmaf(feat[k * 4 + 3], wv.w, a);
        }
        acc = fmaf(fmaxf(a, 0.0f), W2[m], acc);
    }
    out[pix] = acc;
}

// ---------------------------------------------------------------------------
extern "C" void kernel_launch(void* const* d_in, const int* in_sizes, int n_in,
                              void* d_out, int out_size, void* d_ws, size_t ws_size,
                              hipStream_t stream) {
    const float* coords = (const float*)d_in[0];
    const float* lfx    = (const float*)d_in[1];
    const float* lfy    = (const float*)d_in[2];
    const float* plane  = (const float*)d_in[3];
    const float* W1     = (const float*)d_in[4];
    const float* b1     = (const float*)d_in[5];
    const float* W2     = (const float*)d_in[6];
    const float* b2     = (const float*)d_in[7];
    float* out = (float*)d_out;

    const size_t planeBytes = (size_t)ND2 * ND2 * NC * sizeof(float); // 8 MB
    const size_t lineBytes  = (size_t)ND1 * NC * sizeof(float);       // 128 KB
    const size_t need = planeBytes + 2 * lineBytes;

    if (ws_size >= need) {
        float* pl_t = (float*)d_ws;
        float* lx_t = (float*)((char*)d_ws + planeBytes);
        float* ly_t = lx_t + ND1 * NC;
        // d_ws is re-poisoned before every call -> transposes must re-run each call.
        transpose32<<<(ND2 * ND2) / 64, 256, 0, stream>>>(plane, pl_t, ND2 * ND2);
        transpose32<<<ND1 / 64, 256, 0, stream>>>(lfx, lx_t, ND1);
        transpose32<<<ND1 / 64, 256, 0, stream>>>(lfy, ly_t, ND1);
        fused_forward<true><<<NPIX / 256, 256, 0, stream>>>(
            coords, lx_t, ly_t, pl_t, W1, b1, W2, b2, out);
    } else {
        fused_forward<false><<<NPIX / 256, 256, 0, stream>>>(
            coords, lfx, lfy, plane, W1, b1, W2, b2, out);
    }
}

// Round 3
// 262.309 us; speedup vs baseline: 1.4512x; 1.4512x over previous
//
#include <hip/hip_runtime.h>

// Problem constants (from reference)
#define NC   32      // feature channels
#define ND1  1024    // line resolution
#define ND2  256     // plane resolution
#define NM   64      // hidden width
#define NPIX (1024 * 1024)
#define NBUCK 256    // 16x16 buckets, each 64x64 coordinate units
#define SORTBLK 256  // blocks in hist/scatter; 4096 pixels per block

// ---------------------------------------------------------------------------
// Transpose [32][N] -> [N][32], LDS-tiled. Used for lines (N=1024) and the
// plane viewed as [32][65536].
// ---------------------------------------------------------------------------
__global__ __launch_bounds__(256) void transpose32(const float* __restrict__ in,
                                                   float* __restrict__ out, int N) {
    __shared__ float tile[32][65];
    const int pos0 = blockIdx.x * 64;
    const int tid  = threadIdx.x;
#pragma unroll
    for (int r = 0; r < 8; ++r) {
        int c = r * 4 + (tid >> 6);
        int p = tid & 63;
        tile[c][p] = in[c * N + pos0 + p];
    }
    __syncthreads();
#pragma unroll
    for (int r = 0; r < 8; ++r) {
        int p = r * 8 + (tid >> 5);
        int c = tid & 31;
        out[(pos0 + p) * 32 + c] = tile[c][p];
    }
}

// ---------------------------------------------------------------------------
// Two-level counting sort of pixels by 64x64-coord-unit tile (no global atomics).
// ---------------------------------------------------------------------------
__device__ __forceinline__ int bucket_of(float x, float y) {
    int bx = ((int)x) >> 6;
    int by = ((int)y) >> 6;
    bx = min(max(bx, 0), 15);
    by = min(max(by, 0), 15);
    return by * 16 + bx;
}

// Per-block LDS histogram. blockHist is bucket-major: [NBUCK][SORTBLK].
__global__ __launch_bounds__(256) void hist_kernel(const float2* __restrict__ coords,
                                                   int* __restrict__ blockHist) {
    __shared__ int h[NBUCK];
    const int t = threadIdx.x;
    h[t] = 0;
    __syncthreads();
    const int base = blockIdx.x * 4096;
#pragma unroll
    for (int r = 0; r < 16; ++r) {
        float2 xy = coords[base + r * 256 + t];
        atomicAdd(&h[bucket_of(xy.x, xy.y)], 1);
    }
    __syncthreads();
    blockHist[t * SORTBLK + blockIdx.x] = h[t];
}

// Exclusive scan of 65536 bucket-major entries. One block of 1024 threads,
// 64 entries per thread.
__global__ __launch_bounds__(1024) void scan_kernel(const int* __restrict__ blockHist,
                                                    int* __restrict__ scanned) {
    __shared__ int sums[1024];
    const int t = threadIdx.x;
    const int base = t * 64;
    int local[64];
    int s = 0;
#pragma unroll
    for (int k = 0; k < 64; ++k) { local[k] = blockHist[base + k]; s += local[k]; }
    sums[t] = s;
    __syncthreads();
    for (int d = 1; d < 1024; d <<= 1) {
        int x = (t >= d) ? sums[t - d] : 0;
        __syncthreads();
        sums[t] += x;
        __syncthreads();
    }
    int off = (t > 0) ? sums[t - 1] : 0;
#pragma unroll
    for (int k = 0; k < 64; ++k) { scanned[base + k] = off; off += local[k]; }
}

// Scatter using per-block LDS cursors seeded from the scanned bases.
__global__ __launch_bounds__(256) void scatter_kernel(const float2* __restrict__ coords,
                                                      const int* __restrict__ scanned,
                                                      float2* __restrict__ coords2,
                                                      int* __restrict__ perm) {
    __shared__ int cur[NBUCK];
    const int t = threadIdx.x;
    cur[t] = scanned[t * SORTBLK + blockIdx.x];
    __syncthreads();
    const int base = blockIdx.x * 4096;
#pragma unroll
    for (int r = 0; r < 16; ++r) {
        const int pix = base + r * 256 + t;
        float2 xy = coords[pix];
        const int b = bucket_of(xy.x, xy.y);
        const int dst = atomicAdd(&cur[b], 1);   // LDS atomic, cheap
        coords2[dst] = xy;
        perm[dst] = pix;
    }
}

// ---------------------------------------------------------------------------
// Fused: line-x * line-y + plane  ->  Linear(32->64) -> ReLU -> Linear(64->1)
// MODE 0: raw layout. MODE 1: transposed tables. MODE 2: transposed + sorted
// pixel order (coords2/perm) so plane gathers are L2-local.
// ---------------------------------------------------------------------------
template <int MODE>
__global__ __launch_bounds__(256, 2) void fused_forward(
    const float* __restrict__ coords,   // MODE 2: sorted coords2
    const float* __restrict__ lx,
    const float* __restrict__ ly,
    const float* __restrict__ pl,
    const float* __restrict__ W1,    // [64][32]
    const float* __restrict__ b1,    // [64]
    const float* __restrict__ W2,    // [64]
    const float* __restrict__ b2,    // [1]
    float* __restrict__ out,
    const int* __restrict__ perm)    // MODE 2 only
{
    const int i = blockIdx.x * 256 + threadIdx.x;
    const float2 xy = reinterpret_cast<const float2*>(coords)[i];
    const float xn = xy.x * (2.0f / 1024.0f) - 1.0f;
    const float yn = xy.y * (2.0f / 1024.0f) - 1.0f;

    // ---- 1D line interp (border clamp, align_corners) ----
    float posx = fminf(fmaxf((xn + 1.0f) * 0.5f * 1023.0f, 0.0f), 1023.0f);
    int   ix   = min((int)posx, 1022);
    float wx   = posx - (float)ix;
    float omwx = 1.0f - wx;

    float posy = fminf(fmaxf((yn + 1.0f) * 0.5f * 1023.0f, 0.0f), 1023.0f);
    int   iy   = min((int)posy, 1022);
    float wy   = posy - (float)iy;
    float omwy = 1.0f - wy;

    // ---- plane bilinear (zeros padding, align_corners) ----
    float px  = (xn + 1.0f) * 0.5f * 255.0f;
    float py  = (yn + 1.0f) * 0.5f * 255.0f;
    float fx0 = floorf(px), fy0 = floorf(py);
    int   x0 = (int)fx0, y0 = (int)fy0;
    float pwx = px - fx0, pwy = py - fy0;
    int   x1 = x0 + 1, y1 = y0 + 1;
    float vx0 = (x0 >= 0 && x0 < ND2) ? 1.0f : 0.0f;
    float vx1 = (x1 >= 0 && x1 < ND2) ? 1.0f : 0.0f;
    float vy0 = (y0 >= 0 && y0 < ND2) ? 1.0f : 0.0f;
    float vy1 = (y1 >= 0 && y1 < ND2) ? 1.0f : 0.0f;
    int xc0 = min(max(x0, 0), ND2 - 1), xc1 = min(max(x1, 0), ND2 - 1);
    int yc0 = min(max(y0, 0), ND2 - 1), yc1 = min(max(y1, 0), ND2 - 1);
    float w00 = (1.0f - pwy) * (1.0f - pwx) * vy0 * vx0;
    float w01 = (1.0f - pwy) * pwx          * vy0 * vx1;
    float w10 = pwy          * (1.0f - pwx) * vy1 * vx0;
    float w11 = pwy          * pwx          * vy1 * vx1;

    float feat[NC];

    if (MODE >= 1) {
        const float4* ax0 = (const float4*)(lx + ix * NC);
        const float4* ax1 = (const float4*)(lx + (ix + 1) * NC);
        const float4* ay0 = (const float4*)(ly + iy * NC);
        const float4* ay1 = (const float4*)(ly + (iy + 1) * NC);
        const float4* p00 = (const float4*)(pl + (yc0 * ND2 + xc0) * NC);
        const float4* p01 = (const float4*)(pl + (yc0 * ND2 + xc1) * NC);
        const float4* p10 = (const float4*)(pl + (yc1 * ND2 + xc0) * NC);
        const float4* p11 = (const float4*)(pl + (yc1 * ND2 + xc1) * NC);
#pragma unroll
        for (int k = 0; k < 8; ++k) {
            float4 a0 = ax0[k], a1 = ax1[k];
            float4 c0 = ay0[k], c1 = ay1[k];
            float4 q00 = p00[k], q01 = p01[k], q10 = p10[k], q11 = p11[k];
#define FEAT_COMP(j, comp)                                                   \
            {                                                                \
                float fxv = a0.comp * omwx + a1.comp * wx;                   \
                float fyv = c0.comp * omwy + c1.comp * wy;                   \
                float fpv = q00.comp * w00 + q01.comp * w01 +                \
                            q10.comp * w10 + q11.comp * w11;                 \
                feat[k * 4 + j] = fxv * fyv + fpv;                           \
            }
            FEAT_COMP(0, x) FEAT_COMP(1, y) FEAT_COMP(2, z) FEAT_COMP(3, w)
#undef FEAT_COMP
        }
    } else {
#pragma unroll
        for (int c = 0; c < NC; ++c) {
            float a0 = lx[c * ND1 + ix],  a1 = lx[c * ND1 + ix + 1];
            float c0 = ly[c * ND1 + iy],  c1 = ly[c * ND1 + iy + 1];
            const float* ps = pl + c * (ND2 * ND2);
            float q00 = ps[yc0 * ND2 + xc0], q01 = ps[yc0 * ND2 + xc1];
            float q10 = ps[yc1 * ND2 + xc0], q11 = ps[yc1 * ND2 + xc1];
            float fxv = a0 * omwx + a1 * wx;
            float fyv = c0 * omwy + c1 * wy;
            feat[c] = fxv * fyv + (q00 * w00 + q01 * w01 + q10 * w10 + q11 * w11);
        }
    }

    // ---- decoder: h = relu(W1 @ feat + b1); out = W2 @ h + b2 ----
    float acc = b2[0];
#pragma unroll 4
    for (int m = 0; m < NM; ++m) {
        const float4* wrow = (const float4*)(W1 + m * NC);
        float a = b1[m];
#pragma unroll
        for (int k = 0; k < 8; ++k) {
            float4 wv = wrow[k];
            a = fmaf(feat[k * 4 + 0], wv.x, a);
            a = fmaf(feat[k * 4 + 1], wv.y, a);
            a = fmaf(feat[k * 4 + 2], wv.z, a);
            a = fmaf(feat[k * 4 + 3], wv.w, a);
        }
        acc = fmaf(fmaxf(a, 0.0f), W2[m], acc);
    }

    if (MODE == 2)
        out[perm[i]] = acc;     // scattered 4B write, absorbed by L2 (out=4MB)
    else
        out[i] = acc;
}

// ---------------------------------------------------------------------------
extern "C" void kernel_launch(void* const* d_in, const int* in_sizes, int n_in,
                              void* d_out, int out_size, void* d_ws, size_t ws_size,
                              hipStream_t stream) {
    const float* coords = (const float*)d_in[0];
    const float* lfx    = (const float*)d_in[1];
    const float* lfy    = (const float*)d_in[2];
    const float* plane  = (const float*)d_in[3];
    const float* W1     = (const float*)d_in[4];
    const float* b1     = (const float*)d_in[5];
    const float* W2     = (const float*)d_in[6];
    const float* b2     = (const float*)d_in[7];
    float* out = (float*)d_out;

    const size_t planeBytes  = (size_t)ND2 * ND2 * NC * sizeof(float); // 8 MB
    const size_t lineBytes   = (size_t)ND1 * NC * sizeof(float);       // 128 KB
    const size_t coordsBytes = (size_t)NPIX * 2 * sizeof(float);       // 8 MB
    const size_t permBytes   = (size_t)NPIX * sizeof(int);             // 4 MB
    const size_t histBytes   = (size_t)NBUCK * SORTBLK * sizeof(int);  // 256 KB
    const size_t needTrans  = planeBytes + 2 * lineBytes;
    const size_t needSorted = needTrans + coordsBytes + permBytes + 2 * histBytes;

    if (ws_size >= needSorted) {
        char* p = (char*)d_ws;
        float*  pl_t      = (float*)p;               p += planeBytes;
        float*  lx_t      = (float*)p;               p += lineBytes;
        float*  ly_t      = (float*)p;               p += lineBytes;
        float2* coords2   = (float2*)p;              p += coordsBytes;
        int*    perm      = (int*)p;                 p += permBytes;
        int*    blockHist = (int*)p;                 p += histBytes;
        int*    scanned   = (int*)p;

        // ws is re-poisoned each call -> everything rebuilt every call.
        hist_kernel<<<SORTBLK, 256, 0, stream>>>((const float2*)coords, blockHist);
        scan_kernel<<<1, 1024, 0, stream>>>(blockHist, scanned);
        scatter_kernel<<<SORTBLK, 256, 0, stream>>>((const float2*)coords, scanned,
                                                    coords2, perm);
        transpose32<<<(ND2 * ND2) / 64, 256, 0, stream>>>(plane, pl_t, ND2 * ND2);
        transpose32<<<ND1 / 64, 256, 0, stream>>>(lfx, lx_t, ND1);
        transpose32<<<ND1 / 64, 256, 0, stream>>>(lfy, ly_t, ND1);
        fused_forward<2><<<NPIX / 256, 256, 0, stream>>>(
            (const float*)coords2, lx_t, ly_t, pl_t, W1, b1, W2, b2, out, perm);
    } else if (ws_size >= needTrans) {
        float* pl_t = (float*)d_ws;
        float* lx_t = (float*)((char*)d_ws + planeBytes);
        float* ly_t = lx_t + ND1 * NC;
        transpose32<<<(ND2 * ND2) / 64, 256, 0, stream>>>(plane, pl_t, ND2 * ND2);
        transpose32<<<ND1 / 64, 256, 0, stream>>>(lfx, lx_t, ND1);
        transpose32<<<ND1 / 64, 256, 0, stream>>>(lfy, ly_t, ND1);
        fused_forward<1><<<NPIX / 256, 256, 0, stream>>>(
            coords, lx_t, ly_t, pl_t, W1, b1, W2, b2, out, nullptr);
    } else {
        fused_forward<0><<<NPIX / 256, 256, 0, stream>>>(
            coords, lfx, lfy, plane, W1, b1, W2, b2, out, nullptr);
    }
}

// Round 4
// 242.008 us; speedup vs baseline: 1.5729x; 1.0839x over previous
//
#include <hip/hip_runtime.h>

// Problem constants (from reference)
#define NC   32      // feature channels
#define ND1  1024    // line resolution
#define ND2  256     // plane resolution
#define NM   64      // hidden width
#define NPIX (1024 * 1024)
#define NBUCK 256    // 16x16 coarse buckets, each 64x64 coordinate units
#define SORTBLK 64   // blocks in coarse hist/scatter; 16384 pixels per block

// ---------------------------------------------------------------------------
// Transpose [32][N] -> [N][32], LDS-tiled.
// ---------------------------------------------------------------------------
__global__ __launch_bounds__(256) void transpose32(const float* __restrict__ in,
                                                   float* __restrict__ out, int N) {
    __shared__ float tile[32][65];
    const int pos0 = blockIdx.x * 64;
    const int tid  = threadIdx.x;
#pragma unroll
    for (int r = 0; r < 8; ++r) {
        int c = r * 4 + (tid >> 6);
        int p = tid & 63;
        tile[c][p] = in[c * N + pos0 + p];
    }
    __syncthreads();
#pragma unroll
    for (int r = 0; r < 8; ++r) {
        int p = r * 8 + (tid >> 5);
        int c = tid & 31;
        out[(pos0 + p) * 32 + c] = tile[c][p];
    }
}

// Both line tables in one launch: blockIdx.y selects lx/ly.
__global__ __launch_bounds__(256) void transpose32_lines(
    const float* __restrict__ inx, const float* __restrict__ iny,
    float* __restrict__ outx, float* __restrict__ outy) {
    const float* in  = blockIdx.y ? iny : inx;
    float*       out = blockIdx.y ? outy : outx;
    __shared__ float tile[32][65];
    const int pos0 = blockIdx.x * 64;
    const int tid  = threadIdx.x;
#pragma unroll
    for (int r = 0; r < 8; ++r) {
        int c = r * 4 + (tid >> 6);
        int p = tid & 63;
        tile[c][p] = in[c * ND1 + pos0 + p];
    }
    __syncthreads();
#pragma unroll
    for (int r = 0; r < 8; ++r) {
        int p = r * 8 + (tid >> 5);
        int c = tid & 31;
        out[(pos0 + p) * 32 + c] = tile[c][p];
    }
}

// ---------------------------------------------------------------------------
// Coarse counting sort (two-level, no global atomics), then per-bucket fine
// sort by 4x4-coord-unit cell (= one plane texel).
// ---------------------------------------------------------------------------
__device__ __forceinline__ int clampi(int v, int lo, int hi) {
    return min(max(v, lo), hi);
}
__device__ __forceinline__ int bucket_of(float x, float y) {
    int xi = clampi((int)x, 0, 1023);
    int yi = clampi((int)y, 0, 1023);
    return (yi >> 6) * 16 + (xi >> 6);
}
__device__ __forceinline__ int finecell_of(float x, float y) {
    int xi = clampi((int)x, 0, 1023);
    int yi = clampi((int)y, 0, 1023);
    return ((yi >> 2) & 15) * 16 + ((xi >> 2) & 15);
}

// Per-block LDS histogram. blockHist is bucket-major: [NBUCK][SORTBLK].
__global__ __launch_bounds__(1024) void hist_kernel(const float2* __restrict__ coords,
                                                    int* __restrict__ blockHist) {
    __shared__ int h[NBUCK];
    const int t = threadIdx.x;
    if (t < NBUCK) h[t] = 0;
    __syncthreads();
    const int base = blockIdx.x * 16384;
#pragma unroll
    for (int r = 0; r < 16; ++r) {
        float2 xy = coords[base + r * 1024 + t];
        atomicAdd(&h[bucket_of(xy.x, xy.y)], 1);
    }
    __syncthreads();
    if (t < NBUCK) blockHist[t * SORTBLK + blockIdx.x] = h[t];
}

// Exclusive scan of NBUCK*SORTBLK = 16384 bucket-major entries; one block.
__global__ __launch_bounds__(1024) void scan_kernel(const int* __restrict__ blockHist,
                                                    int* __restrict__ scanned) {
    __shared__ int sums[1024];
    const int t = threadIdx.x;
    const int base = t * 16;
    int local[16];
    int s = 0;
#pragma unroll
    for (int k = 0; k < 16; ++k) { local[k] = blockHist[base + k]; s += local[k]; }
    sums[t] = s;
    __syncthreads();
    for (int d = 1; d < 1024; d <<= 1) {
        int x = (t >= d) ? sums[t - d] : 0;
        __syncthreads();
        sums[t] += x;
        __syncthreads();
    }
    int off = (t > 0) ? sums[t - 1] : 0;
#pragma unroll
    for (int k = 0; k < 16; ++k) { scanned[base + k] = off; off += local[k]; }
}

// Coarse scatter using per-block LDS cursors seeded from scanned bases.
__global__ __launch_bounds__(1024) void scatter_kernel(const float2* __restrict__ coords,
                                                       const int* __restrict__ scanned,
                                                       float2* __restrict__ coords2,
                                                       int* __restrict__ perm) {
    __shared__ int cur[NBUCK];
    const int t = threadIdx.x;
    if (t < NBUCK) cur[t] = scanned[t * SORTBLK + blockIdx.x];
    __syncthreads();
    const int base = blockIdx.x * 16384;
#pragma unroll
    for (int r = 0; r < 16; ++r) {
        const int pix = base + r * 1024 + t;
        float2 xy = coords[pix];
        const int b = bucket_of(xy.x, xy.y);
        const int dst = atomicAdd(&cur[b], 1);   // LDS atomic
        coords2[dst] = xy;
        perm[dst] = pix;
    }
}

// Fine sort: one block per coarse bucket; counting sort over 256 fine cells
// entirely in LDS. Reads coarse-sorted coords2/perm, writes coords3/perm2.
__global__ __launch_bounds__(1024) void fine_sort_kernel(
    const float2* __restrict__ coords2, const int* __restrict__ perm,
    const int* __restrict__ scanned,
    float2* __restrict__ coords3, int* __restrict__ perm2) {
    __shared__ int h[256];
    __shared__ int sc[256];
    const int t = threadIdx.x;
    const int b = blockIdx.x;
    const int start = scanned[b * SORTBLK];
    const int end   = (b == NBUCK - 1) ? NPIX : scanned[(b + 1) * SORTBLK];
    if (t < 256) h[t] = 0;
    __syncthreads();
    for (int i = start + t; i < end; i += 1024) {
        float2 xy = coords2[i];
        atomicAdd(&h[finecell_of(xy.x, xy.y)], 1);
    }
    __syncthreads();
    if (t < 256) sc[t] = h[t];
    __syncthreads();
    for (int d = 1; d < 256; d <<= 1) {
        int v = 0;
        if (t >= d && t < 256) v = sc[t - d];
        __syncthreads();
        if (t < 256) sc[t] += v;
        __syncthreads();
    }
    // h becomes the global write cursor per fine cell (exclusive base).
    if (t < 256) h[t] = start + sc[t] - h[t];
    __syncthreads();
    for (int i = start + t; i < end; i += 1024) {
        float2 xy = coords2[i];
        const int c = finecell_of(xy.x, xy.y);
        const int dst = atomicAdd(&h[c], 1);
        coords3[dst] = xy;
        perm2[dst] = perm[i];
    }
}

// ---------------------------------------------------------------------------
// Fused: line-x * line-y + plane  ->  Linear(32->64) -> ReLU -> Linear(64->1)
// MODE 0: raw layout. MODE 1: transposed tables. MODE 2: transposed + sorted
// pixel order (sorted coords + perm) so gathers are cacheline-local.
// ---------------------------------------------------------------------------
template <int MODE>
__global__ __launch_bounds__(256, 2) void fused_forward(
    const float* __restrict__ coords,   // MODE 2: sorted coords
    const float* __restrict__ lx,
    const float* __restrict__ ly,
    const float* __restrict__ pl,
    const float* __restrict__ W1,    // [64][32]
    const float* __restrict__ b1,    // [64]
    const float* __restrict__ W2,    // [64]
    const float* __restrict__ b2,    // [1]
    float* __restrict__ out,
    const int* __restrict__ perm)    // MODE 2 only
{
    const int i = blockIdx.x * 256 + threadIdx.x;
    const float2 xy = reinterpret_cast<const float2*>(coords)[i];
    const float xn = xy.x * (2.0f / 1024.0f) - 1.0f;
    const float yn = xy.y * (2.0f / 1024.0f) - 1.0f;

    // ---- 1D line interp (border clamp, align_corners) ----
    float posx = fminf(fmaxf((xn + 1.0f) * 0.5f * 1023.0f, 0.0f), 1023.0f);
    int   ix   = min((int)posx, 1022);
    float wx   = posx - (float)ix;
    float omwx = 1.0f - wx;

    float posy = fminf(fmaxf((yn + 1.0f) * 0.5f * 1023.0f, 0.0f), 1023.0f);
    int   iy   = min((int)posy, 1022);
    float wy   = posy - (float)iy;
    float omwy = 1.0f - wy;

    // ---- plane bilinear (zeros padding, align_corners) ----
    float px  = (xn + 1.0f) * 0.5f * 255.0f;
    float py  = (yn + 1.0f) * 0.5f * 255.0f;
    float fx0 = floorf(px), fy0 = floorf(py);
    int   x0 = (int)fx0, y0 = (int)fy0;
    float pwx = px - fx0, pwy = py - fy0;
    int   x1 = x0 + 1, y1 = y0 + 1;
    float vx0 = (x0 >= 0 && x0 < ND2) ? 1.0f : 0.0f;
    float vx1 = (x1 >= 0 && x1 < ND2) ? 1.0f : 0.0f;
    float vy0 = (y0 >= 0 && y0 < ND2) ? 1.0f : 0.0f;
    float vy1 = (y1 >= 0 && y1 < ND2) ? 1.0f : 0.0f;
    int xc0 = clampi(x0, 0, ND2 - 1), xc1 = clampi(x1, 0, ND2 - 1);
    int yc0 = clampi(y0, 0, ND2 - 1), yc1 = clampi(y1, 0, ND2 - 1);
    float w00 = (1.0f - pwy) * (1.0f - pwx) * vy0 * vx0;
    float w01 = (1.0f - pwy) * pwx          * vy0 * vx1;
    float w10 = pwy          * (1.0f - pwx) * vy1 * vx0;
    float w11 = pwy          * pwx          * vy1 * vx1;

    float feat[NC];

    if (MODE >= 1) {
        const float4* ax0 = (const float4*)(lx + ix * NC);
        const float4* ax1 = (const float4*)(lx + (ix + 1) * NC);
        const float4* ay0 = (const float4*)(ly + iy * NC);
        const float4* ay1 = (const float4*)(ly + (iy + 1) * NC);
        const float4* p00 = (const float4*)(pl + (yc0 * ND2 + xc0) * NC);
        const float4* p01 = (const float4*)(pl + (yc0 * ND2 + xc1) * NC);
        const float4* p10 = (const float4*)(pl + (yc1 * ND2 + xc0) * NC);
        const float4* p11 = (const float4*)(pl + (yc1 * ND2 + xc1) * NC);
#pragma unroll
        for (int k = 0; k < 8; ++k) {
            float4 a0 = ax0[k], a1 = ax1[k];
            float4 c0 = ay0[k], c1 = ay1[k];
            float4 q00 = p00[k], q01 = p01[k], q10 = p10[k], q11 = p11[k];
#define FEAT_COMP(j, comp)                                                   \
            {                                                                \
                float fxv = a0.comp * omwx + a1.comp * wx;                   \
                float fyv = c0.comp * omwy + c1.comp * wy;                   \
                float fpv = q00.comp * w00 + q01.comp * w01 +                \
                            q10.comp * w10 + q11.comp * w11;                 \
                feat[k * 4 + j] = fxv * fyv + fpv;                           \
            }
            FEAT_COMP(0, x) FEAT_COMP(1, y) FEAT_COMP(2, z) FEAT_COMP(3, w)
#undef FEAT_COMP
        }
    } else {
#pragma unroll
        for (int c = 0; c < NC; ++c) {
            float a0 = lx[c * ND1 + ix],  a1 = lx[c * ND1 + ix + 1];
            float c0 = ly[c * ND1 + iy],  c1 = ly[c * ND1 + iy + 1];
            const float* ps = pl + c * (ND2 * ND2);
            float q00 = ps[yc0 * ND2 + xc0], q01 = ps[yc0 * ND2 + xc1];
            float q10 = ps[yc1 * ND2 + xc0], q11 = ps[yc1 * ND2 + xc1];
            float fxv = a0 * omwx + a1 * wx;
            float fyv = c0 * omwy + c1 * wy;
            feat[c] = fxv * fyv + (q00 * w00 + q01 * w01 + q10 * w10 + q11 * w11);
        }
    }

    // ---- decoder: h = relu(W1 @ feat + b1); out = W2 @ h + b2 ----
    // W1/b1/W2/b2 addresses are thread-uniform -> scalar (SGPR) loads.
    float acc = b2[0];
#pragma unroll 4
    for (int m = 0; m < NM; ++m) {
        const float4* wrow = (const float4*)(W1 + m * NC);
        float a = b1[m];
#pragma unroll
        for (int k = 0; k < 8; ++k) {
            float4 wv = wrow[k];
            a = fmaf(feat[k * 4 + 0], wv.x, a);
            a = fmaf(feat[k * 4 + 1], wv.y, a);
            a = fmaf(feat[k * 4 + 2], wv.z, a);
            a = fmaf(feat[k * 4 + 3], wv.w, a);
        }
        acc = fmaf(fmaxf(a, 0.0f), W2[m], acc);
    }

    if (MODE == 2)
        out[perm[i]] = acc;     // scattered 4B write, absorbed by L2 (out=4MB)
    else
        out[i] = acc;
}

// ---------------------------------------------------------------------------
extern "C" void kernel_launch(void* const* d_in, const int* in_sizes, int n_in,
                              void* d_out, int out_size, void* d_ws, size_t ws_size,
                              hipStream_t stream) {
    const float* coords = (const float*)d_in[0];
    const float* lfx    = (const float*)d_in[1];
    const float* lfy    = (const float*)d_in[2];
    const float* plane  = (const float*)d_in[3];
    const float* W1     = (const float*)d_in[4];
    const float* b1     = (const float*)d_in[5];
    const float* W2     = (const float*)d_in[6];
    const float* b2     = (const float*)d_in[7];
    float* out = (float*)d_out;

    const size_t planeBytes  = (size_t)ND2 * ND2 * NC * sizeof(float); // 8 MB
    const size_t lineBytes   = (size_t)ND1 * NC * sizeof(float);       // 128 KB
    const size_t coordsBytes = (size_t)NPIX * 2 * sizeof(float);       // 8 MB
    const size_t permBytes   = (size_t)NPIX * sizeof(int);             // 4 MB
    const size_t histBytes   = (size_t)NBUCK * SORTBLK * sizeof(int);  // 64 KB
    const size_t needTrans  = planeBytes + 2 * lineBytes;
    const size_t needCoarse = needTrans + coordsBytes + permBytes + 2 * histBytes;
    const size_t needFine   = needCoarse + coordsBytes + permBytes;

    if (ws_size >= needCoarse) {
        char* p = (char*)d_ws;
        float*  pl_t      = (float*)p;               p += planeBytes;
        float*  lx_t      = (float*)p;               p += lineBytes;
        float*  ly_t      = (float*)p;               p += lineBytes;
        float2* coords2   = (float2*)p;              p += coordsBytes;
        int*    perm      = (int*)p;                 p += permBytes;
        int*    blockHist = (int*)p;                 p += histBytes;
        int*    scanned   = (int*)p;                 p += histBytes;
        float2* coords3   = (float2*)p;              p += coordsBytes;
        int*    perm2     = (int*)p;

        // ws is re-poisoned each call -> everything rebuilt every call.
        hist_kernel<<<SORTBLK, 1024, 0, stream>>>((const float2*)coords, blockHist);
        scan_kernel<<<1, 1024, 0, stream>>>(blockHist, scanned);
        scatter_kernel<<<SORTBLK, 1024, 0, stream>>>((const float2*)coords, scanned,
                                                     coords2, perm);
        transpose32<<<(ND2 * ND2) / 64, 256, 0, stream>>>(plane, pl_t, ND2 * ND2);
        transpose32_lines<<<dim3(ND1 / 64, 2), 256, 0, stream>>>(lfx, lfy, lx_t, ly_t);
        if (ws_size >= needFine) {
            fine_sort_kernel<<<NBUCK, 1024, 0, stream>>>(coords2, perm, scanned,
                                                         coords3, perm2);
            fused_forward<2><<<NPIX / 256, 256, 0, stream>>>(
                (const float*)coords3, lx_t, ly_t, pl_t, W1, b1, W2, b2, out, perm2);
        } else {
            fused_forward<2><<<NPIX / 256, 256, 0, stream>>>(
                (const float*)coords2, lx_t, ly_t, pl_t, W1, b1, W2, b2, out, perm);
        }
    } else if (ws_size >= needTrans) {
        float* pl_t = (float*)d_ws;
        float* lx_t = (float*)((char*)d_ws + planeBytes);
        float* ly_t = lx_t + ND1 * NC;
        transpose32<<<(ND2 * ND2) / 64, 256, 0, stream>>>(plane, pl_t, ND2 * ND2);
        transpose32_lines<<<dim3(ND1 / 64, 2), 256, 0, stream>>>(lfx, lfy, lx_t, ly_t);
        fused_forward<1><<<NPIX / 256, 256, 0, stream>>>(
            coords, lx_t, ly_t, pl_t, W1, b1, W2, b2, out, nullptr);
    } else {
        fused_forward<0><<<NPIX / 256, 256, 0, stream>>>(
            coords, lfx, lfy, plane, W1, b1, W2, b2, out, nullptr);
    }
}